// Round 9
// baseline (893.161 us; speedup 1.0000x reference)
//
#include <hip/hip_runtime.h>
#include <hip/hip_bf16.h>
#include <math.h>

// SwinTransformer3D block, bf16-MFMA, direct-from-global fragment GEMMs
// (no LDS, no barriers in any GEMM — attn_k's proven pattern applied to all).
// B=8 T=8 H=56 W=56 C=128, window (2,7,7) -> N=98 (pad 112), shift (1,3,3),
// HEADS=4, d=32. TOK = 2048*98 = 200704 tokens.
//
// ws layout (bytes):
//   P0 = 0          : xw / attnO / xn2 (bf16 TOK*128), reused serially
//   P1 = 51,381,248 : q  bf16 [bwh*98+n][32]   | later: h bf16 TOK*512
//   P2 = P1+51,381,248 : k  bf16 same
//   P3 = P2+51,381,248 : Vt bf16 [bwh*32+d][112]
//   PW = 256,902,144 : bf16 weights (qkv/proj/fc1/fc2)
// Residual y lives in d_out (fp32); fc2 does in-place add.

#define TOK 200704
#define SCALE_Q 0.17677669529663687f

typedef __attribute__((ext_vector_type(8))) short bf16x8;
typedef __attribute__((ext_vector_type(4))) float f32x4;

__device__ __forceinline__ short f2b(float f) {
    __hip_bfloat16 h = __float2bfloat16(f);
    return *reinterpret_cast<short*>(&h);
}

// tanh-form GELU via hardware exp (validated: absmax 0.031 << 0.109 thresh).
__device__ __forceinline__ float gelu_f(float v) {
    float u = 1.5957691216057308f * (v + 0.044715f * v * v * v);
    return v / (1.f + __expf(-u));
}

// token (win*98+n) -> float offset of its ORIGINAL spatial position
// (window reverse + roll-back; also the gather map for LN1+roll+partition).
__device__ __forceinline__ size_t spatial_off(int tok) {
    int win = tok / 98;
    int n = tok - win * 98;
    int b = win >> 8;
    int widx = win & 255;
    int t_blk = widx >> 6;
    int h_blk = (widx >> 3) & 7;
    int w_blk = widx & 7;
    int tt = (n >= 49) ? 1 : 0;
    int r = n - tt * 49;
    int hh = r / 7;
    int ww = r - hh * 7;
    int t = t_blk * 2 + tt;
    int hc = h_blk * 7 + hh;
    int wc = w_blk * 7 + ww;
    int tf = (t + 1) & 7;
    int hf = hc + 3; if (hf >= 56) hf -= 56;
    int wf = wc + 3; if (wf >= 56) wf -= 56;
    return ((((size_t)b * 8 + tf) * 56 + hf) * 56 + wf) * 128;
}

__global__ __launch_bounds__(256) void cvt_k(const float* __restrict__ s,
                                             short* __restrict__ d, int n) {
    int i = blockIdx.x * 256 + threadIdx.x;
    if (i < n) d[i] = f2b(s[i]);
}

// LayerNorm (one wave per token, 2 ch/lane) -> bf16 output.
// WIN=1: gather input via spatial_off (LN1 + roll + window partition).
template <int WIN>
__global__ __launch_bounds__(256) void ln_k(const float* __restrict__ src,
                                            const float* __restrict__ g,
                                            const float* __restrict__ b,
                                            short* __restrict__ dst) {
    int tok = blockIdx.x * 4 + (threadIdx.x >> 6);
    int lane = threadIdx.x & 63;
    const float* sp = WIN ? (src + spatial_off(tok)) : (src + (size_t)tok * 128);
    float2 v = *(const float2*)(sp + lane * 2);
    float s = v.x + v.y;
    float q = v.x * v.x + v.y * v.y;
#pragma unroll
    for (int o = 32; o > 0; o >>= 1) {
        s += __shfl_xor(s, o);
        q += __shfl_xor(q, o);
    }
    float mean = s * 0.0078125f;
    float var = q * 0.0078125f - mean * mean;
    float rstd = rsqrtf(var + 1e-5f);
    float2 gv = *(const float2*)(g + lane * 2);
    float2 bv = *(const float2*)(b + lane * 2);
    short2 o2;
    o2.x = f2b((v.x - mean) * rstd * gv.x + bv.x);
    o2.y = f2b((v.y - mean) * rstd * gv.y + bv.y);
    *(short2*)(dst + (size_t)tok * 128 + lane * 2) = o2;
}

// Direct-fragment bf16 MFMA GEMM: C[M,N] = A[M,K] @ W[N,K]^T + bias.
// NO LDS, NO BARRIERS: each lane loads its MFMA fragment (16B contiguous)
// straight from global; weights + A re-reads are L2/L3-resident; compiler
// software-pipelines loads under MFMAs freely.
// Block 256 thr = 4 waves; block tile 128x128; wave tile 64x64.
// MODE 0: QKV -> q,k (bf16 [bwh*98+n][32], q scaled) + Vt (bf16 [bwh*32+d][112])
// MODE 1: proj + x residual, spatial scatter -> y (fp32, = d_out)
// MODE 2: fc1 + GELU -> h bf16
// MODE 3: fc2 + y residual (in-place RMW) -> d_out fp32
template <int MODE, int KDIM>
__global__ __launch_bounds__(256) void dgemm(const short* __restrict__ A,
                                             const short* __restrict__ Wt,
                                             const float* __restrict__ bias,
                                             void* __restrict__ Optr,
                                             const float* __restrict__ E0,
                                             short* __restrict__ O2,
                                             short* __restrict__ O3) {
    const int tid = threadIdx.x;
    const int nb = blockIdx.x, mb = blockIdx.y;
    const int lane = tid & 63;
    const int wid = tid >> 6;
    const int wr = wid >> 1, wc = wid & 1;
    const int l15 = lane & 15, kg = lane >> 4;

    f32x4 zf = {0.f, 0.f, 0.f, 0.f};
    f32x4 acc[4][4];
#pragma unroll
    for (int i = 0; i < 4; i++)
#pragma unroll
        for (int j = 0; j < 4; j++) acc[i][j] = zf;

    // lane's fragment bases: row (l15 within 16-band), cols kg*8..kg*8+7
    const short* Ab = A + (size_t)(mb * 128 + wr * 64 + l15) * KDIM + kg * 8;
    const short* Wb = Wt + (size_t)(nb * 128 + wc * 64 + l15) * KDIM + kg * 8;

    for (int k0 = 0; k0 < KDIM; k0 += 32) {
        bf16x8 af[4], bfr[4];
#pragma unroll
        for (int mi = 0; mi < 4; mi++)
            af[mi] = *(const bf16x8*)(Ab + (size_t)mi * 16 * KDIM + k0);
#pragma unroll
        for (int ni = 0; ni < 4; ni++)
            bfr[ni] = *(const bf16x8*)(Wb + (size_t)ni * 16 * KDIM + k0);
#pragma unroll
        for (int mi = 0; mi < 4; mi++)
#pragma unroll
            for (int ni = 0; ni < 4; ni++)
                acc[mi][ni] = __builtin_amdgcn_mfma_f32_16x16x32_bf16(
                    af[mi], bfr[ni], acc[mi][ni], 0, 0, 0);
    }

#pragma unroll
    for (int mi = 0; mi < 4; mi++) {
#pragma unroll
        for (int r = 0; r < 4; r++) {
            int gr = mb * 128 + wr * 64 + mi * 16 + kg * 4 + r;
            size_t so = 0;
            if constexpr (MODE == 1) so = spatial_off(gr);
#pragma unroll
            for (int ni = 0; ni < 4; ni++) {
                int gc = nb * 128 + wc * 64 + ni * 16 + l15;
                float v = acc[mi][ni][r] + bias[gc];
                if constexpr (MODE == 0) {
                    int which = gc >> 7;
                    int head = (gc >> 5) & 3;
                    int dd = gc & 31;
                    int lwin = gr / 98;
                    int n = gr - lwin * 98;
                    size_t bwh = (size_t)lwin * 4 + head;
                    if (which == 0) {
                        ((short*)Optr)[(bwh * 98 + n) * 32 + dd] = f2b(v * SCALE_Q);
                    } else if (which == 1) {
                        O2[(bwh * 98 + n) * 32 + dd] = f2b(v);
                    } else {
                        O3[(bwh * 32 + dd) * 112 + n] = f2b(v);
                    }
                } else if constexpr (MODE == 1) {
                    float* Of = (float*)Optr;
                    Of[so + gc] = v + E0[so + gc];
                } else if constexpr (MODE == 2) {
                    ((short*)Optr)[(size_t)gr * 512 + gc] = f2b(gelu_f(v));
                } else {
                    float* Of = (float*)Optr;
                    size_t o = (size_t)gr * 128 + gc;
                    Of[o] = v + Of[o];
                }
            }
        }
    }
}

// Attention: block = window (4 waves = 4 heads). N=98 padded to 112.
// Unchanged from round 6 (passed; below the top-line cost).
__global__ __launch_bounds__(256) void attn_k(const short* __restrict__ Qb,
                                              const short* __restrict__ Kb,
                                              const short* __restrict__ Vt,
                                              const float* __restrict__ rpb,
                                              short* __restrict__ O) {
    __shared__ short P_lds[4][16 * 136];
    __shared__ float rbias[4][508];
    const int win = blockIdx.x;
    const int tid = threadIdx.x;
    const int head = tid >> 6;
    const int lane = tid & 63;
    const int l15 = lane & 15, kg = lane >> 4;
    const size_t bwh = (size_t)win * 4 + head;
    const int widx = win & 255;
    const int t_blk = widx >> 6, h_blk = (widx >> 3) & 7, w_blk = widx & 7;
    short* Pw = P_lds[head];

    for (int i = lane; i < 507; i += 64) rbias[head][i] = rpb[i * 4 + head];
#pragma unroll
    for (int i = 0; i < 4; i++) {
        int idx = lane * 4 + i;
        Pw[(idx >> 4) * 136 + 112 + (idx & 15)] = 0;
    }

    const short* Kg = Kb + bwh * 3136;
    bf16x8 kf[7];
#pragma unroll
    for (int b = 0; b < 7; b++)
        kf[b] = *(const bf16x8*)(Kg + (b * 16 + l15) * 32 + kg * 8);
    const short* Vg = Vt + bwh * 3584;
    bf16x8 vf[2][4];
#pragma unroll
    for (int nt = 0; nt < 2; nt++)
#pragma unroll
        for (int ks = 0; ks < 4; ks++)
            vf[nt][ks] = *(const bf16x8*)(Vg + (nt * 16 + l15) * 112 + ks * 32 + kg * 8);

    int cm_t[7], cm_h[7], cm_w[7], creg[7];
    bool cvalid[7];
#pragma unroll
    for (int b = 0; b < 7; b++) {
        int n = b * 16 + l15;
        cvalid[b] = (n < 98);
        int nn = cvalid[b] ? n : 0;
        int tt = (nn >= 49) ? 1 : 0;
        int r = nn - tt * 49;
        int hh = r / 7;
        int ww = r - hh * 7;
        cm_t[b] = tt; cm_h[b] = hh; cm_w[b] = ww;
        int ct = (t_blk == 3) ? (1 + tt) : 0;
        int ch = (h_blk == 7) ? ((hh <= 3) ? 1 : 2) : 0;
        int cw = (w_blk == 7) ? ((ww <= 3) ? 1 : 2) : 0;
        creg[b] = ct * 9 + ch * 3 + cw;
    }

    const short* Qg = Qb + bwh * 3136;
    f32x4 zf = {0.f, 0.f, 0.f, 0.f};

    for (int a = 0; a < 7; a++) {
        bf16x8 qf = *(const bf16x8*)(Qg + (a * 16 + l15) * 32 + kg * 8);
        f32x4 s[7];
#pragma unroll
        for (int b = 0; b < 7; b++)
            s[b] = __builtin_amdgcn_mfma_f32_16x16x32_bf16(qf, kf[b], zf, 0, 0, 0);

        float p[7][4], mx[4], sm[4];
#pragma unroll
        for (int r = 0; r < 4; r++) {
            int m = a * 16 + kg * 4 + r;
            int mm = (m < 98) ? m : 0;
            int tt = (mm >= 49) ? 1 : 0;
            int rr = mm - tt * 49;
            int hh = rr / 7;
            int ww = rr - hh * 7;
            int ct = (t_blk == 3) ? (1 + tt) : 0;
            int ch = (h_blk == 7) ? ((hh <= 3) ? 1 : 2) : 0;
            int cw = (w_blk == 7) ? ((ww <= 3) ? 1 : 2) : 0;
            int rreg = ct * 9 + ch * 3 + cw;
            float mxv = -1e30f;
#pragma unroll
            for (int b = 0; b < 7; b++) {
                float v;
                if (cvalid[b]) {
                    int bidx = (tt - cm_t[b] + 1) * 169 + (hh - cm_h[b] + 6) * 13 +
                               (ww - cm_w[b] + 6);
                    v = s[b][r] + rbias[head][bidx] +
                        ((rreg == creg[b]) ? 0.f : -100.f);
                } else {
                    v = -1e30f;
                }
                p[b][r] = v;
                mxv = fmaxf(mxv, v);
            }
            mx[r] = mxv;
        }
#pragma unroll
        for (int r = 0; r < 4; r++) {
#pragma unroll
            for (int off = 1; off < 16; off <<= 1)
                mx[r] = fmaxf(mx[r], __shfl_xor(mx[r], off));
        }
#pragma unroll
        for (int r = 0; r < 4; r++) {
            float ss = 0.f;
#pragma unroll
            for (int b = 0; b < 7; b++) {
                float e = __expf(p[b][r] - mx[r]);
                p[b][r] = e;
                ss += e;
            }
            sm[r] = ss;
        }
#pragma unroll
        for (int r = 0; r < 4; r++) {
#pragma unroll
            for (int off = 1; off < 16; off <<= 1) sm[r] += __shfl_xor(sm[r], off);
        }
#pragma unroll
        for (int r = 0; r < 4; r++) {
            float inv = 1.f / sm[r];
#pragma unroll
            for (int b = 0; b < 7; b++)
                Pw[(kg * 4 + r) * 136 + b * 16 + l15] = f2b(p[b][r] * inv);
        }
        asm volatile("" ::: "memory");

        bf16x8 pa[4];
#pragma unroll
        for (int ks = 0; ks < 4; ks++)
            pa[ks] = *(const bf16x8*)&Pw[l15 * 136 + ks * 32 + kg * 8];
        f32x4 o0 = zf, o1 = zf;
#pragma unroll
        for (int ks = 0; ks < 4; ks++) {
            o0 = __builtin_amdgcn_mfma_f32_16x16x32_bf16(pa[ks], vf[0][ks], o0, 0, 0, 0);
            o1 = __builtin_amdgcn_mfma_f32_16x16x32_bf16(pa[ks], vf[1][ks], o1, 0, 0, 0);
        }
        asm volatile("" ::: "memory");
#pragma unroll
        for (int r = 0; r < 4; r++) {
            int m = a * 16 + kg * 4 + r;
            if (m < 98) {
                size_t base = ((size_t)win * 98 + m) * 128 + head * 32;
                O[base + l15] = f2b(o0[r]);
                O[base + 16 + l15] = f2b(o1[r]);
            }
        }
    }
}

extern "C" void kernel_launch(void* const* d_in, const int* in_sizes, int n_in,
                              void* d_out, int out_size, void* d_ws, size_t ws_size,
                              hipStream_t stream) {
    const float* x      = (const float*)d_in[0];
    const float* ln1_g  = (const float*)d_in[2];
    const float* ln1_b  = (const float*)d_in[3];
    const float* qkv_w  = (const float*)d_in[4];
    const float* qkv_b  = (const float*)d_in[5];
    const float* rpb    = (const float*)d_in[6];
    const float* proj_w = (const float*)d_in[7];
    const float* proj_b = (const float*)d_in[8];
    const float* ln2_g  = (const float*)d_in[9];
    const float* ln2_b  = (const float*)d_in[10];
    const float* fc1_w  = (const float*)d_in[11];
    const float* fc1_b  = (const float*)d_in[12];
    const float* fc2_w  = (const float*)d_in[13];
    const float* fc2_b  = (const float*)d_in[14];
    float* out = (float*)d_out;   // residual y lives here

    char* ws = (char*)d_ws;
    const size_t P1 = 51381248;          // q  (later h)
    const size_t P2 = P1 + 51381248;     // k
    const size_t P3 = P2 + 51381248;     // Vt
    const size_t PW = 256902144;         // weights

    short* xw    = (short*)ws;           // also attnO, xn2 (serial reuse)
    short* q     = (short*)(ws + P1);
    short* k     = (short*)(ws + P2);
    short* Vt    = (short*)(ws + P3);
    short* h     = (short*)(ws + P1);    // q/k/Vt dead by fc1
    short* wq    = (short*)(ws + PW);            // 49152 elems
    short* wp    = (short*)(ws + PW + 98304);    // 16384
    short* w1    = (short*)(ws + PW + 131072);   // 65536
    short* w2    = (short*)(ws + PW + 262144);   // 65536

    cvt_k<<<(49152 + 255) / 256, 256, 0, stream>>>(qkv_w, wq, 49152);
    cvt_k<<<(16384 + 255) / 256, 256, 0, stream>>>(proj_w, wp, 16384);
    cvt_k<<<(65536 + 255) / 256, 256, 0, stream>>>(fc1_w, w1, 65536);
    cvt_k<<<(65536 + 255) / 256, 256, 0, stream>>>(fc2_w, w2, 65536);

    // LN1 + roll + window partition
    ln_k<1><<<TOK / 4, 256, 0, stream>>>(x, ln1_g, ln1_b, xw);
    // QKV GEMM (M=200704, N=384, K=128) -> q, k, Vt
    dgemm<0, 128><<<dim3(3, 1568), 256, 0, stream>>>(xw, wq, qkv_b, (void*)q,
                                                     nullptr, k, Vt);
    // attention -> attnO (reuses xw region)
    attn_k<<<2048, 256, 0, stream>>>(q, k, Vt, rpb, xw);
    // proj + residual -> y (= d_out, fp32), spatial scatter
    dgemm<1, 128><<<dim3(1, 1568), 256, 0, stream>>>(xw, wp, proj_b, (void*)out,
                                                     x, nullptr, nullptr);
    // LN2 -> xn2 bf16 (reuses xw region)
    ln_k<0><<<TOK / 4, 256, 0, stream>>>(out, ln2_g, ln2_b, xw);
    // fc1 + GELU -> h bf16 (N=512, K=128)
    dgemm<2, 128><<<dim3(4, 1568), 256, 0, stream>>>(xw, w1, fc1_b, (void*)h,
                                                     nullptr, nullptr, nullptr);
    // fc2 + residual (in-place on d_out) (N=128, K=512)
    dgemm<3, 512><<<dim3(1, 1568), 256, 0, stream>>>(h, w2, fc2_b, (void*)out,
                                                     nullptr, nullptr, nullptr);
}